// Round 8
// baseline (901.249 us; speedup 1.0000x reference)
//
#include <hip/hip_runtime.h>

#define HIDDEN 128
#define TSTEPS 512
#define NFUT 50
#define BR 16          // 16 rows/block: G0 = rows 0-7, G1 = rows 8-15 (independent chains)
#define THREADS 512    // 8 waves: 0-3 MFMA-role, 4-7 ew-role (1 of each per SIMD)
#define HPITCH 136     // h row pitch bf16 (272B, 16B-aligned)
#define APITCH 132     // acc gate-segment pitch f32 (528B, 16B-aligned)
#define AROW (4*APITCH) // acc row pitch f32

typedef __bf16 bf16x8 __attribute__((ext_vector_type(8)));
typedef float floatx4 __attribute__((ext_vector_type(4)));
typedef float f32x2 __attribute__((ext_vector_type(2)));

union B8 { int4 i; bf16x8 v; };

#if defined(__has_builtin)
#  if __has_builtin(__builtin_amdgcn_exp2f)
#    define EXP2F(x) __builtin_amdgcn_exp2f(x)
#  else
#    define EXP2F(x) exp2f(x)
#  endif
#  if __has_builtin(__builtin_amdgcn_rcpf)
#    define RCPF(x) __builtin_amdgcn_rcpf(x)
#  else
#    define RCPF(x) (1.0f / (x))
#  endif
#  if __has_builtin(__builtin_amdgcn_s_setprio)
#    define SETPRIO(p) __builtin_amdgcn_s_setprio(p)
#  else
#    define SETPRIO(p)
#  endif
#else
#  define EXP2F(x) exp2f(x)
#  define RCPF(x) (1.0f / (x))
#  define SETPRIO(p)
#endif

#define L2E  1.4426950408889634f
#define L2E2 2.8853900817779268f

// (512,1): arg2 = min blocks/CU (R4 evidence: (512,4)->cap 64, (512,2)->cap 128).
// 1 block x 8 waves = 2 waves/SIMD -> VGPR cap 256. MFMA-waves need ~200.
__global__ __launch_bounds__(THREADS, 1)
void lstm_forecast_kernel(const float* __restrict__ x,
                          const float* __restrict__ W_ih,
                          const float* __restrict__ W_hh,
                          const float* __restrict__ b_ih,
                          const float* __restrict__ b_hh,
                          const float* __restrict__ fc_w,
                          const float* __restrict__ fc_b,
                          float* __restrict__ out) {
    // LDS: xa 64KB + h 2x4.25KB + acc 2x16.5KB + fcw 1KB ~= 107KB (1 block/CU)
    __shared__ __align__(16) uint2  xa[TSTEPS * BR];        // bf16 hi/lo splits of x
    __shared__ __align__(16) __bf16 h_lds[2][16 * HPITCH];  // per-group h; rows 8-15 stay 0
    __shared__ __align__(16) float  acc_lds[2][8 * AROW];   // per-group raw gates (f32)
    __shared__ __align__(16) float  fcw_lds[2][HIDDEN];

    const int tid  = threadIdx.x;
    const int wave = tid >> 6;
    const int lane = tid & 63;
    const int quad = lane >> 4;
    const int l15  = lane & 15;
    const int rb   = blockIdx.x * BR;
    const bool mrole = (wave < 4);      // waves 0-3: MFMA producers; 4-7: ew consumers

    if (tid < 256) fcw_lds[tid >> 7][tid & 127] = fc_w[tid];

    // ---- stage x as bf16 hi/lo splits: xa[t][row0..15] ----
    {
        const int row = tid & 15;
        for (int tb = tid >> 4; tb < TSTEPS; tb += THREADS >> 4) {
            float2 xv = *(const float2*)&x[(size_t)(rb + row) * (2 * TSTEPS) + tb * 2];
            __bf16 x0h = (__bf16)xv.x, x1h = (__bf16)xv.y;
            __bf16 x0r = (__bf16)(xv.x - (float)x0h);
            __bf16 x1r = (__bf16)(xv.y - (float)x1h);
            uint2 d;
            d.x = (unsigned)__builtin_bit_cast(unsigned short, x0h) |
                  ((unsigned)__builtin_bit_cast(unsigned short, x1h) << 16);
            d.y = (unsigned)__builtin_bit_cast(unsigned short, x0r) |
                  ((unsigned)__builtin_bit_cast(unsigned short, x1r) << 16);
            xa[tb * BR + row] = d;
        }
    }
    // zero both h buffers fully (rows 8-15 are permanent zero padding for N=16 MFMA)
    for (int i = tid; i < 2 * 16 * HPITCH; i += THREADS) (&h_lds[0][0])[i] = (__bf16)0.0f;

    float gs[4];
    const float fcb0 = fc_b[0], fcb1 = fc_b[1];
#pragma unroll
    for (int g = 0; g < 4; ++g) gs[g] = (g == 2) ? -L2E2 : -L2E;

    // ---- MFMA-role: weights -> registers (2 sets of 16 gate-cols per wave) ----
    // Transposed MFMA: A = weights (m = gate col = wave*32+s*16+l15), B = h rows.
    // C layout: n(=l15) = batch row (0-7 real), m(=quad*4+reg) = col offset.
    bf16x8 bfrag[2][4][4];   // [set][gate][kchunk] gs-scaled W_hh (later W_eff)
    B8 bfx[2][4];            // gs-scaled W_ih + bias hi/lo (quad0 k-slots)
    if (mrole) {
#pragma unroll
        for (int s = 0; s < 2; ++s) {
            const int ub = wave * 32 + s * 16 + l15;
#pragma unroll
            for (int g = 0; g < 4; ++g) {
                const int cg = g * HIDDEN + ub;
                const float w0 = W_ih[cg * 2 + 0];
                const float w1 = W_ih[cg * 2 + 1];
                const float bs = b_ih[cg] + b_hh[cg];
#pragma unroll
                for (int ks = 0; ks < 4; ++ks) {
                    const float* wp = W_hh + (size_t)cg * HIDDEN + ks * 32 + quad * 8;
                    bf16x8 bb;
#pragma unroll
                    for (int j = 0; j < 8; ++j) bb[j] = (__bf16)(gs[g] * wp[j]);
                    bfrag[s][g][ks] = bb;
                }
                B8 t; t.i = make_int4(0, 0, 0, 0);
                if (quad == 0) {
                    const float w0s = gs[g] * w0, w1s = gs[g] * w1, bss = gs[g] * bs;
                    __bf16 w0h = (__bf16)w0s, w1h = (__bf16)w1s;
                    __bf16 w0l = (__bf16)(w0s - (float)w0h);
                    __bf16 w1l = (__bf16)(w1s - (float)w1h);
                    __bf16 bh  = (__bf16)bss;
                    __bf16 bl  = (__bf16)(bss - (float)bh);
                    bf16x8 bv = {w0h, w1h, bh, bl, w0h, w1h, w0l, w1l};
                    t.v = bv;
                }
                bfx[s][g] = t;
            }
        }
    }

    // ---- ew-role mapping: thread = (row 0-7, col-quad 0-31) of the active group ----
    const int erow = lane & 7;
    const int cq   = (wave - 4) * 8 + (lane >> 3);   // meaningful for ew waves only
    f32x2 cstA[2] = {{0.f, 0.f}, {0.f, 0.f}};        // G0 cell state (2 pairs)
    f32x2 cstB[2] = {{0.f, 0.f}, {0.f, 0.f}};        // G1 cell state

    const unsigned ones2 = 0x3F803F80u;
    const floatx4 z = {0.f, 0.f, 0.f, 0.f};

    auto pk2 = [](f32x2 hn) -> unsigned {
        return (unsigned)__builtin_bit_cast(unsigned short, (__bf16)hn.x)
             | ((unsigned)__builtin_bit_cast(unsigned short, (__bf16)hn.y) << 16);
    };
    // combine one packed pair (2 cells); cst passed by ref -> statically indexed
    auto pairC = [&](f32x2 eap, f32x2 ecp, f32x2 ebp, f32x2 eop, f32x2& c) -> unsigned {
        const f32x2 A1 = 1.f + eap, B1 = 1.f + ebp, C1 = 1.f + ecp;
        const f32x2 P  = A1 * B1;
        const f32x2 PC = P * C1;
        f32x2 R;
        { const float I = RCPF(PC.x * PC.y); R.x = I * PC.y; R.y = I * PC.x; }
        const f32x2 sfv = P * R;                  // sigmoid(f)
        const f32x2 igv = (1.f - ebp) * (C1 * R); // sigmoid(i)*tanh(g)
        const f32x2 cn  = sfv * c + igv;
        c = cn;
        const f32x2 am = -L2E2 * cn;
        f32x2 ed;
        ed.x = EXP2F(fminf(am.x, 29.f));          // c clamp (tanh err < 4e-9)
        ed.y = EXP2F(fminf(am.y, 29.f));
        const f32x2 E = (1.f + ed) * (1.f + eop);
        f32x2 R2;
        { const float J = RCPF(E.x * E.y); R2.x = J * E.y; R2.y = J * E.x; }
        const f32x2 hn = (1.f - ed) * R2;         // sigmoid(o)*tanh(c)
        return pk2(hn);
    };

    // ew consumer: read 4 gates x 4 cols from acc_lds[eg], ew 4 cells, b64 h-write
    auto cellW = [&](const int eg, f32x2& c0, f32x2& c1) {
        const float* ab = &acc_lds[eg][erow * AROW + cq * 4];
        const floatx4 a0 = *(const floatx4*)&ab[0 * APITCH];
        const floatx4 a1 = *(const floatx4*)&ab[1 * APITCH];
        const floatx4 a2 = *(const floatx4*)&ab[2 * APITCH];
        const floatx4 a3 = *(const floatx4*)&ab[3 * APITCH];
        floatx4 ea, ec, eb, eo;                   // breadth-first exps (max ILP)
#pragma unroll
        for (int r = 0; r < 4; ++r) ea[r] = EXP2F(a0[r]);
#pragma unroll
        for (int r = 0; r < 4; ++r) ec[r] = EXP2F(a1[r]);
#pragma unroll
        for (int r = 0; r < 4; ++r) eb[r] = EXP2F(a2[r]);
#pragma unroll
        for (int r = 0; r < 4; ++r) eo[r] = EXP2F(a3[r]);
        f32x2 t0, t1, t2, t3;
        t0.x = ea[0]; t0.y = ea[1]; t1.x = ec[0]; t1.y = ec[1];
        t2.x = eb[0]; t2.y = eb[1]; t3.x = eo[0]; t3.y = eo[1];
        const unsigned lo = pairC(t0, t1, t2, t3, c0);
        t0.x = ea[2]; t0.y = ea[3]; t1.x = ec[2]; t1.y = ec[3];
        t2.x = eb[2]; t2.y = eb[3]; t3.x = eo[2]; t3.y = eo[3];
        const unsigned hi = pairC(t0, t1, t2, t3, c1);
        uint2 wv; wv.x = lo; wv.y = hi;
        *(uint2*)&h_lds[eg][erow * HPITCH + cq * 4] = wv;   // 4 cols, one b64
    };

    // MFMA producer (encode): W-MFMAs first (8 indep chains), x+bias MFMAs last
    // (xd LDS latency fully hidden), store 8 b128 of raw gates to acc_lds[mg].
    auto cellM = [&](const int mg, const int t) {
        const uint2 xd = xa[t * BR + mg * 8 + (l15 & 7)];
        bf16x8 af[4];
#pragma unroll
        for (int ks = 0; ks < 4; ++ks)
            af[ks] = *(const bf16x8*)&h_lds[mg][l15 * HPITCH + ks * 32 + quad * 8];
        floatx4 acc[2][4];
        SETPRIO(1);
#pragma unroll
        for (int s = 0; s < 2; ++s)
#pragma unroll
            for (int g = 0; g < 4; ++g)
                acc[s][g] = __builtin_amdgcn_mfma_f32_16x16x32_bf16(bfrag[s][g][0], af[0], z, 0, 0, 0);
#pragma unroll
        for (int ks = 1; ks < 4; ++ks)
#pragma unroll
            for (int s = 0; s < 2; ++s)
#pragma unroll
                for (int g = 0; g < 4; ++g)
                    acc[s][g] = __builtin_amdgcn_mfma_f32_16x16x32_bf16(bfrag[s][g][ks], af[ks], acc[s][g], 0, 0, 0);
        B8 xf; xf.i = make_int4((int)xd.x, (int)ones2, (int)xd.y, (int)xd.x);
#pragma unroll
        for (int s = 0; s < 2; ++s)
#pragma unroll
            for (int g = 0; g < 4; ++g)
                acc[s][g] = __builtin_amdgcn_mfma_f32_16x16x32_bf16(bfx[s][g].v, xf.v, acc[s][g], 0, 0, 0);
        SETPRIO(0);
        if (l15 < 8) {
#pragma unroll
            for (int s = 0; s < 2; ++s)
#pragma unroll
                for (int g = 0; g < 4; ++g)
                    *(floatx4*)&acc_lds[mg][l15 * AROW + g * APITCH + wave * 32 + s * 16 + quad * 4] = acc[s][g];
        }
    };

    __syncthreads();

    // ================= encode: 1024 pipelined iters =================
    // iter i: MFMA group (i&1) step i>>1  ||  ew group !(i&1) (gates from prev iter)
    if (mrole) cellM(0, 0);                      // iter 0 (ew idle)
    __syncthreads();
    for (int k = 0; k < 511; ++k) {
        if (mrole) cellM(1, k); else cellW(0, cstA[0], cstA[1]);   // iter 2k+1
        __syncthreads();
        if (mrole) cellM(0, k + 1); else cellW(1, cstB[0], cstB[1]); // iter 2k+2
        __syncthreads();
    }
    if (mrole) cellM(1, 511); else cellW(0, cstA[0], cstA[1]);     // iter 1023
    __syncthreads();
    // (G1 step-511 gates pending in acc_lds[1] -> consumed at first forecast iter)

    // ========== transition: fold fc into weights (MFMA-waves only) =========
    floatx4 beff[2][4];
    if (mrole) {
#pragma unroll
        for (int s = 0; s < 2; ++s) {
            const int ub = wave * 32 + s * 16 + l15;
#pragma unroll
            for (int g = 0; g < 4; ++g) {
                const int cgA = g * HIDDEN + ub;
                const float wi0 = W_ih[cgA * 2 + 0];
                const float wi1 = W_ih[cgA * 2 + 1];
#pragma unroll
                for (int ks = 0; ks < 4; ++ks) {
                    const int k0 = ks * 32 + quad * 8;
                    bf16x8 bb = bfrag[s][g][ks];
#pragma unroll
                    for (int j = 0; j < 8; ++j)
                        bb[j] = (__bf16)((float)bb[j] + gs[g] * (wi0 * fcw_lds[0][k0 + j]
                                                               + wi1 * fcw_lds[1][k0 + j]));
                    bfrag[s][g][ks] = bb;
                }
                floatx4 v;
#pragma unroll
                for (int r = 0; r < 4; ++r) {
                    const int cg = g * HIDDEN + wave * 32 + s * 16 + quad * 4 + r;
                    v[r] = gs[g] * (b_ih[cg] + b_hh[cg]
                                  + W_ih[cg * 2 + 0] * fcb0 + W_ih[cg * 2 + 1] * fcb1);
                }
                beff[s][g] = v;
            }
        }
    }

    // MFMA producer (forecast): emit y from af (h BEFORE this cell), beff C-init
    auto cellMF = [&](const int mg, const int kf) {
        bf16x8 af[4];
#pragma unroll
        for (int ks = 0; ks < 4; ++ks)
            af[ks] = *(const bf16x8*)&h_lds[mg][l15 * HPITCH + ks * 32 + quad * 8];
        if (wave == 0) {                          // y(kf) = fc . h  (this iter's af)
            float p0 = 0.f, p1 = 0.f;
#pragma unroll
            for (int ks = 0; ks < 4; ++ks) {
#pragma unroll
                for (int j = 0; j < 8; ++j) {
                    const float hv = (float)af[ks][j];
                    p0 += hv * fcw_lds[0][ks * 32 + quad * 8 + j];
                    p1 += hv * fcw_lds[1][ks * 32 + quad * 8 + j];
                }
            }
            p0 += __shfl_xor(p0, 16); p0 += __shfl_xor(p0, 32);
            p1 += __shfl_xor(p1, 16); p1 += __shfl_xor(p1, 32);
            if (lane < 8) {
                float* op = &out[(size_t)(rb + mg * 8 + lane) * (2 * NFUT) + kf * 2];
                op[0] = p0 + fcb0;
                op[1] = p1 + fcb1;
            }
        }
        floatx4 acc[2][4];
        SETPRIO(1);
#pragma unroll
        for (int s = 0; s < 2; ++s)
#pragma unroll
            for (int g = 0; g < 4; ++g)
                acc[s][g] = __builtin_amdgcn_mfma_f32_16x16x32_bf16(bfrag[s][g][0], af[0], beff[s][g], 0, 0, 0);
#pragma unroll
        for (int ks = 1; ks < 4; ++ks)
#pragma unroll
            for (int s = 0; s < 2; ++s)
#pragma unroll
                for (int g = 0; g < 4; ++g)
                    acc[s][g] = __builtin_amdgcn_mfma_f32_16x16x32_bf16(bfrag[s][g][ks], af[ks], acc[s][g], 0, 0, 0);
        SETPRIO(0);
        if (l15 < 8) {
#pragma unroll
            for (int s = 0; s < 2; ++s)
#pragma unroll
                for (int g = 0; g < 4; ++g)
                    *(floatx4*)&acc_lds[mg][l15 * AROW + g * APITCH + wave * 32 + s * 16 + quad * 4] = acc[s][g];
        }
    };

    // ================= forecast: 100 pipelined iters =================
    for (int k = 0; k < NFUT; ++k) {
        if (mrole) cellMF(0, k); else cellW(1, cstB[0], cstB[1]);  // G1 ew (enc tail / fstep k-1)
        __syncthreads();
        if (mrole) cellMF(1, k); else cellW(0, cstA[0], cstA[1]);  // G0 ew fstep k
        __syncthreads();
    }
}

extern "C" void kernel_launch(void* const* d_in, const int* in_sizes, int n_in,
                              void* d_out, int out_size, void* d_ws, size_t ws_size,
                              hipStream_t stream) {
    const float* x    = (const float*)d_in[0];
    const float* W_ih = (const float*)d_in[1];
    const float* W_hh = (const float*)d_in[2];
    const float* b_ih = (const float*)d_in[3];
    const float* b_hh = (const float*)d_in[4];
    const float* fc_w = (const float*)d_in[5];
    const float* fc_b = (const float*)d_in[6];
    float* out = (float*)d_out;

    const int B = in_sizes[0] / (TSTEPS * 2);   // 4096
    const int grid = B / BR;                    // 256 blocks, 1 per CU
    lstm_forecast_kernel<<<grid, THREADS, 0, stream>>>(x, W_ih, W_hh, b_ih, b_hh, fc_w, fc_b, out);
}

// Round 9
// 490.667 us; speedup vs baseline: 1.8368x; 1.8368x over previous
//
#include <hip/hip_runtime.h>

#define HIDDEN 128
#define TSTEPS 512
#define NFUT 50
#define BR 16          // batch rows per block
#define THREADS 512    // 8 waves, 2/SIMD (R3 structure — best verified: 477us)
#define HPITCH 136     // h row pitch in bf16 (272B rows: 16B-aligned for b128)

typedef __bf16 bf16x8 __attribute__((ext_vector_type(8)));
typedef float floatx4 __attribute__((ext_vector_type(4)));
typedef float f32x2 __attribute__((ext_vector_type(2)));

union B8 { int4 i; bf16x8 v; };

#if defined(__has_builtin)
#  if __has_builtin(__builtin_amdgcn_exp2f)
#    define EXP2F(x) __builtin_amdgcn_exp2f(x)
#  else
#    define EXP2F(x) exp2f(x)
#  endif
#  if __has_builtin(__builtin_amdgcn_rcpf)
#    define RCPF(x) __builtin_amdgcn_rcpf(x)
#  else
#    define RCPF(x) (1.0f / (x))
#  endif
#  if __has_builtin(__builtin_amdgcn_s_setprio)
#    define SETPRIO(p) __builtin_amdgcn_s_setprio(p)
#  else
#    define SETPRIO(p)
#  endif
#else
#  define EXP2F(x) exp2f(x)
#  define RCPF(x) (1.0f / (x))
#  define SETPRIO(p)
#endif

#define L2E  1.4426950408889634f
#define L2E2 2.8853900817779268f

__global__ __launch_bounds__(THREADS, 2)
void lstm_forecast_kernel(const float* __restrict__ x,
                          const float* __restrict__ W_ih,
                          const float* __restrict__ W_hh,
                          const float* __restrict__ b_ih,
                          const float* __restrict__ b_hh,
                          const float* __restrict__ fc_w,
                          const float* __restrict__ fc_b,
                          float* __restrict__ out) {
    // LDS: xa 64KB + h 8.5KB + fcw 1KB ~= 74KB -> 1 block/CU
    __shared__ __align__(16) uint2  xa[TSTEPS * BR];        // (x0h,x1h),(x0r,x1r) bf16 splits
    __shared__ __align__(16) __bf16 h_lds[2][BR * HPITCH];  // double-buffered h
    __shared__ __align__(16) float  fcw_lds[2][HIDDEN];

    const int tid  = threadIdx.x;
    const int wave = tid >> 6;          // 0..7, 2 waves share a SIMD
    const int lane = tid & 63;
    const int quad = lane >> 4;
    const int l15  = lane & 15;
    const int rb   = blockIdx.x * BR;

    if (tid < 256) fcw_lds[tid >> 7][tid & 127] = fc_w[tid];

    // ---- stage x as bf16 hi/lo splits: xa[t][row] (feeds the x-MFMA) ----
    {
        const int row = tid & 15;
        for (int tb = tid >> 4; tb < TSTEPS; tb += THREADS >> 4) {
            float2 xv = *(const float2*)&x[(size_t)(rb + row) * (2 * TSTEPS) + tb * 2];
            __bf16 x0h = (__bf16)xv.x, x1h = (__bf16)xv.y;
            __bf16 x0r = (__bf16)(xv.x - (float)x0h);
            __bf16 x1r = (__bf16)(xv.y - (float)x1h);
            uint2 d;
            d.x = (unsigned)__builtin_bit_cast(unsigned short, x0h) |
                  ((unsigned)__builtin_bit_cast(unsigned short, x1h) << 16);
            d.y = (unsigned)__builtin_bit_cast(unsigned short, x0r) |
                  ((unsigned)__builtin_bit_cast(unsigned short, x1r) << 16);
            xa[tb * BR + row] = d;
        }
    }
    for (int i = tid; i < BR * HPITCH; i += THREADS) h_lds[0][i] = (__bf16)0.0f;

    // ---- weights -> registers, pre-scaled so MFMA outputs are exp2-ready ----
    // gate scale: i,f,o -> -log2(e); g -> -2*log2(e)
    // Transposed MFMA: bfrag/bfx = A operand (m = gate col = wave*16 + l15),
    // h/x = B operand (n = batch row = l15).
    // C layout: n(=lane&15) = batch row, m(=quad*4+reg) = gate-col offset.
    bf16x8 bfrag[4][4];   // [gate][kchunk] scaled W_hh (later W_eff)
    B8 bfx[4];            // scaled W_ih + bias hi/lo, quad0 k-slots only (A operand)
    float gs[4];
    const float fcb0 = fc_b[0], fcb1 = fc_b[1];
    const int ub    = wave * 16 + l15;        // A-layout gate col (weights)
    const int cbase = wave * 16 + quad * 4;   // C-layout gate-col base (ew/h-write)
#pragma unroll
    for (int g = 0; g < 4; ++g) {
        gs[g] = (g == 2) ? -L2E2 : -L2E;
        const int cg = g * HIDDEN + ub;
        const float w0 = W_ih[cg * 2 + 0];
        const float w1 = W_ih[cg * 2 + 1];
        const float bs = b_ih[cg] + b_hh[cg];
#pragma unroll
        for (int ks = 0; ks < 4; ++ks) {
            const float* wp = W_hh + (size_t)cg * HIDDEN + ks * 32 + quad * 8;
            bf16x8 bb;
#pragma unroll
            for (int j = 0; j < 8; ++j) bb[j] = (__bf16)(gs[g] * wp[j]);
            bfrag[g][ks] = bb;
        }
        B8 t; t.i = make_int4(0, 0, 0, 0);
        if (quad == 0) {
            const float w0s = gs[g] * w0, w1s = gs[g] * w1, bss = gs[g] * bs;
            __bf16 w0h = (__bf16)w0s, w1h = (__bf16)w1s;
            __bf16 w0l = (__bf16)(w0s - (float)w0h);
            __bf16 w1l = (__bf16)(w1s - (float)w1h);
            __bf16 bh  = (__bf16)bss;
            __bf16 bl  = (__bf16)(bss - (float)bh);
            bf16x8 bv = {w0h, w1h, bh, bl, w0h, w1h, w0l, w1l};
            t.v = bv;
        }
        bfx[g] = t;
    }

    const unsigned ones2 = 0x3F803F80u;  // bf16(1.0) x2
    const int hrow = l15 * HPITCH;
    f32x2 cst[2] = {{0.f, 0.f}, {0.f, 0.f}};   // cell state: pair p = cols cbase+2p..+1

    auto pk2 = [](f32x2 hn) -> unsigned {
        return (unsigned)__builtin_bit_cast(unsigned short, (__bf16)hn.x)
             | ((unsigned)__builtin_bit_cast(unsigned short, (__bf16)hn.y) << 16);
    };

    // Tail of ew: needs gates f (a1v) and o (a3v); P = (1+e^-i)(1+e^-2g) and
    // omb = 1-e^-2g arrive precomputed from the hidden (phase-1) region.
    // Per-element math identical to R3's pairC -> bit-identical results.
    auto ewTail = [&](floatx4 a1v, floatx4 a3v, floatx4 P, floatx4 omb, __bf16* hd) {
        floatx4 ec, eo;
#pragma unroll
        for (int r = 0; r < 4; ++r) ec[r] = EXP2F(a1v[r]);  // e^-f
#pragma unroll
        for (int r = 0; r < 4; ++r) eo[r] = EXP2F(a3v[r]);  // e^-o
        unsigned wArr[2];
#pragma unroll
        for (int p = 0; p < 2; ++p) {
            const f32x2 C1   = {1.f + ec[2 * p], 1.f + ec[2 * p + 1]};
            const f32x2 Pp   = {P[2 * p], P[2 * p + 1]};
            const f32x2 ombp = {omb[2 * p], omb[2 * p + 1]};
            const f32x2 eop  = {eo[2 * p], eo[2 * p + 1]};
            const f32x2 PC = Pp * C1;
            f32x2 R;                                        // batched: 1 rcp per pair
            { const float I = RCPF(PC.x * PC.y); R.x = I * PC.y; R.y = I * PC.x; }
            const f32x2 sfv = Pp * R;                       // sigmoid(f)
            const f32x2 igv = ombp * (C1 * R);              // sigmoid(i)*tanh(g)
            const f32x2 cn  = sfv * cst[p] + igv;
            cst[p] = cn;
            const f32x2 am = -L2E2 * cn;
            f32x2 ed;
            ed.x = EXP2F(fminf(am.x, 29.f));                // c clamped at -10 (tanh err < 4e-9)
            ed.y = EXP2F(fminf(am.y, 29.f));
            const f32x2 E = (1.f + ed) * (1.f + eop);
            f32x2 R2;                                       // batched: 1 rcp per pair
            { const float J = RCPF(E.x * E.y); R2.x = J * E.y; R2.y = J * E.x; }
            const f32x2 hn = (1.f - ed) * R2;               // sigmoid(o)*tanh(c)
            wArr[p] = pk2(hn);
        }
        uint2 wv; wv.x = wArr[0]; wv.y = wArr[1];
        *(uint2*)&hd[hrow + cbase] = wv;                    // 4 cols, one b64
    };

    // Encode cell, gate-pair phased: phase 1 = gates i,g (2 indep 5-MFMA chains);
    // phase 2 = gates f,o. The i/g-dependent exps + P/omb have no dependency on
    // phase-2 accs, so the scheduler can hoist them under phase-2's 10 MFMAs
    // (matrix-pipe busy, issue slots free) -> MFMA/VALU overlap within the wave.
    // R3's ks-outer/g-inner finished all 4 gates simultaneously -> nothing hideable.
    auto cellE = [&](const __bf16* hs, __bf16* hd, uint2 xd, int tn) -> uint2 {
        B8 xf; xf.i = make_int4((int)xd.x, (int)ones2, (int)xd.y, (int)xd.x);
        bf16x8 af[4];
#pragma unroll
        for (int ks = 0; ks < 4; ++ks)
            af[ks] = *(const bf16x8*)&hs[hrow + ks * 32 + quad * 8];
        const floatx4 z = {0.f, 0.f, 0.f, 0.f};
        floatx4 a0, a1, a2, a3;
        SETPRIO(1);
        // ---- phase 1: gates i (g=0), g (g=2) ----
        a0 = __builtin_amdgcn_mfma_f32_16x16x32_bf16(bfx[0].v, xf.v, z, 0, 0, 0);
        a2 = __builtin_amdgcn_mfma_f32_16x16x32_bf16(bfx[2].v, xf.v, z, 0, 0, 0);
#pragma unroll
        for (int ks = 0; ks < 4; ++ks) {
            a0 = __builtin_amdgcn_mfma_f32_16x16x32_bf16(bfrag[0][ks], af[ks], a0, 0, 0, 0);
            a2 = __builtin_amdgcn_mfma_f32_16x16x32_bf16(bfrag[2][ks], af[ks], a2, 0, 0, 0);
        }
        // ---- phase 2: gates f (g=1), o (g=3) ----
        a1 = __builtin_amdgcn_mfma_f32_16x16x32_bf16(bfx[1].v, xf.v, z, 0, 0, 0);
        a3 = __builtin_amdgcn_mfma_f32_16x16x32_bf16(bfx[3].v, xf.v, z, 0, 0, 0);
#pragma unroll
        for (int ks = 0; ks < 4; ++ks) {
            a1 = __builtin_amdgcn_mfma_f32_16x16x32_bf16(bfrag[1][ks], af[ks], a1, 0, 0, 0);
            a3 = __builtin_amdgcn_mfma_f32_16x16x32_bf16(bfrag[3][ks], af[ks], a3, 0, 0, 0);
        }
        // ---- hidden VALU: depends only on a0/a2 (phase-1) ----
        floatx4 ea, eb;
#pragma unroll
        for (int r = 0; r < 4; ++r) ea[r] = EXP2F(a0[r]);   // e^-i
#pragma unroll
        for (int r = 0; r < 4; ++r) eb[r] = EXP2F(a2[r]);   // e^-2g
        const floatx4 A1 = 1.f + ea, B1 = 1.f + eb;
        const floatx4 P  = A1 * B1;
        const floatx4 omb = 1.f - eb;
        const int ts = (tn < TSTEPS) ? tn : 0;
        const uint2 xn = xa[ts * BR + l15];                 // prefetch (consumed next cell)
        ewTail(a1, a3, P, omb, hd);
        SETPRIO(0);
        __syncthreads();
        return xn;
    };

    __syncthreads();

    // ================= encode: 512 steps =================
    uint2 xd = xa[l15];                                     // t = 0
    for (int t = 0; t < TSTEPS; t += 2) {
        xd = cellE(h_lds[0], h_lds[1], xd, t + 1);
        xd = cellE(h_lds[1], h_lds[0], xd, t + 2);
    }

    // ========== transition: fold fc into weights =========
    // W_eff = gs*(W_hh + W_ih*fc_w) (A-layout fold); b_eff in exact fp32 C-layout.
    floatx4 beff[4];
#pragma unroll
    for (int g = 0; g < 4; ++g) {
        const int cgA = g * HIDDEN + ub;
        const float wi0 = W_ih[cgA * 2 + 0];
        const float wi1 = W_ih[cgA * 2 + 1];
#pragma unroll
        for (int ks = 0; ks < 4; ++ks) {
            const int k0 = ks * 32 + quad * 8;
            bf16x8 bb = bfrag[g][ks];
#pragma unroll
            for (int j = 0; j < 8; ++j)
                bb[j] = (__bf16)((float)bb[j] + gs[g] * (wi0 * fcw_lds[0][k0 + j]
                                                       + wi1 * fcw_lds[1][k0 + j]));
            bfrag[g][ks] = bb;
        }
        floatx4 v;
#pragma unroll
        for (int r = 0; r < 4; ++r) {
            const int cg = g * HIDDEN + cbase + r;          // C-layout col
            v[r] = gs[g] * (b_ih[cg] + b_hh[cg]
                          + W_ih[cg * 2 + 0] * fcb0 + W_ih[cg * 2 + 1] * fcb1);
        }
        beff[g] = v;
    }

    // Forecast cell: same gate-pair phasing, beff C-init instead of x-MFMAs.
    auto cellF = [&](const __bf16* hs, __bf16* hd) {
        bf16x8 af[4];
#pragma unroll
        for (int ks = 0; ks < 4; ++ks)
            af[ks] = *(const bf16x8*)&hs[hrow + ks * 32 + quad * 8];
        floatx4 a0 = beff[0], a2 = beff[2];
        SETPRIO(1);
#pragma unroll
        for (int ks = 0; ks < 4; ++ks) {
            a0 = __builtin_amdgcn_mfma_f32_16x16x32_bf16(bfrag[0][ks], af[ks], a0, 0, 0, 0);
            a2 = __builtin_amdgcn_mfma_f32_16x16x32_bf16(bfrag[2][ks], af[ks], a2, 0, 0, 0);
        }
        floatx4 a1 = beff[1], a3 = beff[3];
#pragma unroll
        for (int ks = 0; ks < 4; ++ks) {
            a1 = __builtin_amdgcn_mfma_f32_16x16x32_bf16(bfrag[1][ks], af[ks], a1, 0, 0, 0);
            a3 = __builtin_amdgcn_mfma_f32_16x16x32_bf16(bfrag[3][ks], af[ks], a3, 0, 0, 0);
        }
        floatx4 ea, eb;
#pragma unroll
        for (int r = 0; r < 4; ++r) ea[r] = EXP2F(a0[r]);
#pragma unroll
        for (int r = 0; r < 4; ++r) eb[r] = EXP2F(a2[r]);
        const floatx4 A1 = 1.f + ea, B1 = 1.f + eb;
        const floatx4 P  = A1 * B1;
        const floatx4 omb = 1.f - eb;
        ewTail(a1, a3, P, omb, hd);
        SETPRIO(0);
        __syncthreads();
    };

    // y output only (no feedback): wave0 computes while others run MFMA
    auto emitY = [&](const __bf16* hs, int f) {
        if (wave == 0) {
            const int r = lane & 15, seg = lane >> 4;
            const __bf16* hp = &hs[r * HPITCH + seg * 32];
            float p0 = 0.f, p1 = 0.f;
#pragma unroll
            for (int js = 0; js < 4; ++js) {
                bf16x8 hv = *(const bf16x8*)&hp[js * 8];
                const float4* f0 = (const float4*)&fcw_lds[0][seg * 32 + js * 8];
                const float4* f1 = (const float4*)&fcw_lds[1][seg * 32 + js * 8];
                float4 a0 = f0[0], b0 = f0[1], a1 = f1[0], b1 = f1[1];
                p0 += (float)hv[0]*a0.x + (float)hv[1]*a0.y + (float)hv[2]*a0.z + (float)hv[3]*a0.w
                    + (float)hv[4]*b0.x + (float)hv[5]*b0.y + (float)hv[6]*b0.z + (float)hv[7]*b0.w;
                p1 += (float)hv[0]*a1.x + (float)hv[1]*a1.y + (float)hv[2]*a1.z + (float)hv[3]*a1.w
                    + (float)hv[4]*b1.x + (float)hv[5]*b1.y + (float)hv[6]*b1.z + (float)hv[7]*b1.w;
            }
            p0 += __shfl_xor(p0, 16); p0 += __shfl_xor(p0, 32);
            p1 += __shfl_xor(p1, 16); p1 += __shfl_xor(p1, 32);
            if (seg == 0) {
                float* op = &out[(size_t)(rb + r) * (2 * NFUT) + f * 2];
                op[0] = p0 + fcb0;
                op[1] = p1 + fcb1;
            }
        }
    };

    // ================= forecast: 50 steps ================
    for (int f = 0; f < NFUT; f += 2) {
        emitY(h_lds[0], f);
        cellF(h_lds[0], h_lds[1]);
        emitY(h_lds[1], f + 1);
        cellF(h_lds[1], h_lds[0]);
    }
}

extern "C" void kernel_launch(void* const* d_in, const int* in_sizes, int n_in,
                              void* d_out, int out_size, void* d_ws, size_t ws_size,
                              hipStream_t stream) {
    const float* x    = (const float*)d_in[0];
    const float* W_ih = (const float*)d_in[1];
    const float* W_hh = (const float*)d_in[2];
    const float* b_ih = (const float*)d_in[3];
    const float* b_hh = (const float*)d_in[4];
    const float* fc_w = (const float*)d_in[5];
    const float* fc_b = (const float*)d_in[6];
    float* out = (float*)d_out;

    const int B = in_sizes[0] / (TSTEPS * 2);   // 4096
    const int grid = B / BR;                    // 256 blocks, 1 per CU
    lstm_forecast_kernel<<<grid, THREADS, 0, stream>>>(x, W_ih, W_hh, b_ih, b_hh, fc_w, fc_b, out);
}